// Round 22
// baseline (76.220 us; speedup 1.0000x reference)
//
#include <hip/hip_runtime.h>
#include <hip/hip_bf16.h>

#define EMBED 1024
#define HEADS 16
#define HDIM  64
#define BATCH 4
#define SEQ   1024

typedef __attribute__((ext_vector_type(8))) short  short8;
typedef __attribute__((ext_vector_type(4))) short  short4v;
typedef __attribute__((ext_vector_type(4))) float  float4v;
typedef __attribute__((ext_vector_type(8))) float  float8;
typedef __attribute__((ext_vector_type(2))) __bf16 bf16x2;
typedef __attribute__((ext_vector_type(8))) __bf16 bf16x8;

// f32 -> bf16 via native cast (hardware cvt, RNE)
static __device__ __forceinline__ short cvt1(float f) {
  return __builtin_bit_cast(short, (__bf16)f);
}

// pack two f32 -> bf16x2 in one dword (hardware cvt_pk)
static __device__ __forceinline__ unsigned pkbf(float a, float b) {
  bf16x2 v; v[0] = (__bf16)a; v[1] = (__bf16)b;
  return __builtin_bit_cast(unsigned, v);
}

// single v_exp_f32
static __device__ __forceinline__ float ex2(float x) {
  return __builtin_amdgcn_exp2f(x);
}

static __device__ __forceinline__ short8 cvt8(const float* p) {
  float4v a = *(const float4v*)p;
  float4v b = *(const float4v*)(p + 4);
  float8 f = __builtin_shufflevector(a, b, 0, 1, 2, 3, 4, 5, 6, 7);
  bf16x8 bb = __builtin_convertvector(f, bf16x8);
  return __builtin_bit_cast(short8, bb);
}

// Block barrier WITHOUT vmcnt drain (T4).  Cross-wave deps are LDS-only:
// lgkmcnt(0) retires ds_writes AND ds_reads before s_barrier; global loads
// are consumed only by the issuing wave (compiler inserts counted vmcnt).
static __device__ __forceinline__ void block_sync_lds() {
  __builtin_amdgcn_sched_barrier(0);
  asm volatile("s_waitcnt lgkmcnt(0)" ::: "memory");
  __builtin_amdgcn_s_barrier();
  __builtin_amdgcn_sched_barrier(0);
}

#define QSCL 0.04508422002778011f  // log2(e) / sqrt(EMBED)

// ---------------------------------------------------------------------------
// Kernel 1 (fused preprocessing), 1344 blocks — FROZEN:
//   blocks 0..767     : proj, 4 waves/block, 4 units/wave, W hoisted.
//   blocks 768..1279  : mask -> nibble bytes (1M quads, 8 iters).
//   blocks 1280..1343 : Wu -> bf16.
// K rows stored PERMUTED within each 32-key block:
//   s(o) = ((o>>2)&1)*16 + (o>>3)*4 + (o&3)
// ---------------------------------------------------------------------------
__global__ __launch_bounds__(256) void k_pre(
    const float* __restrict__ values, const float* __restrict__ keys,
    const float* __restrict__ query,
    const float* __restrict__ Wv, const float* __restrict__ Wq,
    const float* __restrict__ Wk, const float* __restrict__ Wu,
    const int* __restrict__ mask,
    short* __restrict__ qp, short* __restrict__ kp, short* __restrict__ vpT,
    unsigned char* __restrict__ maskb, short* __restrict__ wub) {
  const int b = blockIdx.x;
  const int t = threadIdx.x;
  if (b < 768) {
    const int l = t & 63, lr = l & 15, g = l >> 4;
    const int wbase = (b * 4 + (t >> 6)) * 4;
    const int z = wbase >> 12;          // uniform for all 4 units
    const float* in_; const float* Wm;
    if (z == 0)      { in_ = query;  Wm = Wq; }
    else if (z == 1) { in_ = keys;   Wm = Wk; }
    else             { in_ = values; Wm = Wv; }
    const float scl = (z == 0) ? QSCL : 1.0f;

    short8 af0[4], af1[4];
    int hh[4], rr[4];
#pragma unroll
    for (int uu = 0; uu < 4; ++uu) {
      const int rem = (wbase + uu) & 4095;
      hh[uu] = rem & 15;
      rr[uu] = (rem >> 4) * 16;
      af0[uu] = cvt8(in_ + (size_t)(rr[uu] + lr) * EMBED + hh[uu] * HDIM + g * 8);
      af1[uu] = cvt8(in_ + (size_t)(rr[uu] + lr) * EMBED + hh[uu] * HDIM + 32 + g * 8);
    }
    short8 wf0[4], wf1[4];
#pragma unroll
    for (int nt = 0; nt < 4; ++nt) {
      wf0[nt] = cvt8(Wm + (size_t)(nt * 16 + lr) * HDIM + g * 8);
      wf1[nt] = cvt8(Wm + (size_t)(nt * 16 + lr) * HDIM + 32 + g * 8);
    }

#pragma unroll
    for (int uu = 0; uu < 4; ++uu) {
      const int h = hh[uu], r0 = rr[uu];
      const int n = r0 >> 10, s0 = r0 & 1023;
      const int nh = n * HEADS + h;
      float4v acc[4];
#pragma unroll
      for (int nt = 0; nt < 4; ++nt) {
        acc[nt] = (float4v){0.f, 0.f, 0.f, 0.f};
        acc[nt] = __builtin_amdgcn_mfma_f32_16x16x32_bf16(af0[uu], wf0[nt], acc[nt], 0, 0, 0);
        acc[nt] = __builtin_amdgcn_mfma_f32_16x16x32_bf16(af1[uu], wf1[nt], acc[nt], 0, 0, 0);
      }
      if (z == 2) {
#pragma unroll
        for (int nt = 0; nt < 4; ++nt) {
          short4v r;
          r[0]=cvt1(acc[nt][0]); r[1]=cvt1(acc[nt][1]);
          r[2]=cvt1(acc[nt][2]); r[3]=cvt1(acc[nt][3]);
          *(short4v*)(vpT + (size_t)(nh * HDIM + nt * 16 + lr) * SEQ + s0 + g * 4) = r;
        }
      } else {
        short* outp = (z == 0) ? qp : kp;
        const int b8 = ((s0 >> 4) & 1) * 8;
        const int rbase = s0 & ~31;
#pragma unroll
        for (int nt = 0; nt < 4; ++nt)
#pragma unroll
          for (int i = 0; i < 4; ++i) {
            const int row = (z == 0)
                ? (s0 + g * 4 + i)
                : (rbase + (g & 1) * 16 + b8 + (g >> 1) * 4 + i);  // s(o) perm
            outp[(size_t)(nh * SEQ + row) * HDIM + nt * 16 + lr] =
                cvt1(acc[nt][i] * scl);
          }
      }
    }
  } else if (b < 1280) {
    const int q0 = ((b - 768) * 8) * 256 + t;
#pragma unroll
    for (int it = 0; it < 8; ++it) {
      const int q = q0 + it * 256;
      uint4 v = *(const uint4*)(mask + (size_t)q * 4);
      unsigned nib = (v.x ? 1u : 0u) | (v.y ? 2u : 0u) |
                     (v.z ? 4u : 0u) | (v.w ? 8u : 0u);
      maskb[q] = (unsigned char)nib;
    }
  } else {
    const int base = (b - 1280) * 256 + t;
#pragma unroll
    for (int it = 0; it < 16; ++it) {
      int i4 = (base + it * 16384) * 4;
      float4v v = *(const float4v*)(Wu + i4);
      short4v r; r[0]=cvt1(v[0]); r[1]=cvt1(v[1]); r[2]=cvt1(v[2]); r[3]=cvt1(v[3]);
      *(short4v*)(wub + i4) = r;
    }
  }
}

// ---------------------------------------------------------------------------
// Kernel 2: flash attention.  QBLK=128, QG=2, nibble mask, mfma32-PV,
// ones-MFMA l, no max tracking.  4-buffer LDS rotation, one barrier per
// 2 tiles (8 total): issue tiles 2tp+2,2tp+3 at pair-head, publish at
// pair-tail (round-21 fix: previous phasing skipped tiles 4,5).
// Counted-vmcnt barriers.  XCD-swizzled grid (512 blocks, 2/CU; 64KB LDS).
// ---------------------------------------------------------------------------
__global__ __launch_bounds__(256, 2) void k_attn(
    const short* __restrict__ qp, const short* __restrict__ kp,
    const short* __restrict__ vpT, const unsigned char* __restrict__ maskb,
    short* __restrict__ ao) {
  const int bid = blockIdx.x;
  const int work = (bid & 7) * 64 + (bid >> 3);
  const int qt = work & 7, grp = work >> 3;
  const int h = grp & 15, n = grp >> 4;

  const int t256 = threadIdx.x;
  const int w = t256 >> 6, l = t256 & 63, lr = l & 15, g = l >> 4;
  const int nh = n * HEADS + h;
  const int q00 = qt * 128 + w * 16;   // group x covers rows q00 + x*64 + lr
  const short* qb  = qp  + (size_t)nh * SEQ * HDIM;
  const short* kbp = kp  + (size_t)nh * SEQ * HDIM;
  const short* vb  = vpT + (size_t)nh * HDIM * SEQ;
  const unsigned char* mb0 = maskb + (size_t)(n * SEQ + q00 + lr) * 256;

  __shared__ __align__(16) short kls0[4096], kls1[4096], kls2[4096], kls3[4096];
  __shared__ __align__(16) short vls0[4096], vls1[4096], vls2[4096], vls3[4096];

  const int s0 = t256, s1 = t256 + 256;
  const int r0s = s0 >> 3, c0s = s0 & 7, r1s = s1 >> 3, c1s = s1 & 7;
  const int ld0 = r0s * 64 + ((c0s ^ (r0s & 7)) << 3);
  const int ld1 = r1s * 64 + ((c1s ^ (r1s & 7)) << 3);

  const int e = lr & 7;
  const int base0 = lr * 64 + ((g ^ e) << 3);
  const int base1 = lr * 64 + (((4 + g) ^ e) << 3);

  short8 qf0[2], qf1[2];
#pragma unroll
  for (int x = 0; x < 2; ++x) {
    qf0[x] = *(const short8*)(qb + (q00 + x * 64 + lr) * HDIM + g * 8);
    qf1[x] = *(const short8*)(qb + (q00 + x * 64 + lr) * HDIM + 32 + g * 8);
  }

  const short8 ones8 = {0x3F80, 0x3F80, 0x3F80, 0x3F80,
                        0x3F80, 0x3F80, 0x3F80, 0x3F80};

  float4v acc[2][4];
  float4v lac[2];
#pragma unroll
  for (int x = 0; x < 2; ++x) {
    lac[x] = (float4v){0.f, 0.f, 0.f, 0.f};
#pragma unroll
    for (int dt = 0; dt < 4; ++dt) acc[x][dt] = (float4v){0.f, 0.f, 0.f, 0.f};
  }

  auto issue = [&](int tile, short8& K0, short8& K1, short8& V0, short8& V1) {
    const int kn = tile * 64;
    K0 = *(const short8*)(kbp + kn * 64 + s0 * 8);
    K1 = *(const short8*)(kbp + kn * 64 + s1 * 8);
    V0 = *(const short8*)(vb + (size_t)r0s * SEQ + kn + c0s * 8);
    V1 = *(const short8*)(vb + (size_t)r1s * SEQ + kn + c1s * 8);
  };
  auto publish = [&](short* Kd, short* Vd, short8 K0, short8 K1, short8 V0, short8 V1) {
    *(short8*)(Kd + ld0) = K0;
    *(short8*)(Kd + ld1) = K1;
    *(short8*)(Vd + ld0) = V0;
    *(short8*)(Vd + ld1) = V1;
  };
  auto tilec = [&](const short* Kb, const short* Vb, int t) {
    float4v sT[2][4];
#pragma unroll
    for (int a = 0; a < 4; ++a) {
      short8 kf0 = *(const short8*)(Kb + a * 1024 + base0);
      short8 kf1 = *(const short8*)(Kb + a * 1024 + base1);
#pragma unroll
      for (int x = 0; x < 2; ++x) {
        float4v z = (float4v){0.f, 0.f, 0.f, 0.f};
        z = __builtin_amdgcn_mfma_f32_16x16x32_bf16(kf0, qf0[x], z, 0, 0, 0);
        sT[x][a] = __builtin_amdgcn_mfma_f32_16x16x32_bf16(kf1, qf1[x], z, 0, 0, 0);
      }
    }
    short8 pw0[2], pw1[2];
#pragma unroll
    for (int x = 0; x < 2; ++x) {
      uint4 mv = *(const uint4*)(mb0 + (size_t)x * 64 * 256 + t * 16);
      const unsigned wl = (g & 2) ? mv.y : mv.x;
      const unsigned wh = (g & 2) ? mv.w : mv.z;
      const int sh = (g & 1) * 16;
      unsigned dw[8];
#pragma unroll
      for (int a = 0; a < 4; ++a) {
        unsigned ta = ((a & 2) ? wh : wl) >> (sh + (a & 1) * 8);
        float p0 = ex2(sT[x][a][0]); p0 = (ta & 1u) ? p0 : 0.f;
        float p1 = ex2(sT[x][a][1]); p1 = (ta & 2u) ? p1 : 0.f;
        float p2 = ex2(sT[x][a][2]); p2 = (ta & 4u) ? p2 : 0.f;
        float p3 = ex2(sT[x][a][3]); p3 = (ta & 8u) ? p3 : 0.f;
        dw[a * 2]     = pkbf(p0, p1);
        dw[a * 2 + 1] = pkbf(p2, p3);
      }
      __builtin_memcpy(&pw0[x], &dw[0], 16);
      __builtin_memcpy(&pw1[x], &dw[4], 16);
      lac[x] = __builtin_amdgcn_mfma_f32_16x16x32_bf16(ones8, pw0[x], lac[x], 0, 0, 0);
      lac[x] = __builtin_amdgcn_mfma_f32_16x16x32_bf16(ones8, pw1[x], lac[x], 0, 0, 0);
    }
#pragma unroll
    for (int dt = 0; dt < 4; ++dt) {
      short8 vf0 = *(const short8*)(Vb + dt * 1024 + base0);
      short8 vf1 = *(const short8*)(Vb + dt * 1024 + base1);
#pragma unroll
      for (int x = 0; x < 2; ++x) {
        acc[x][dt] = __builtin_amdgcn_mfma_f32_16x16x32_bf16(vf0, pw0[x], acc[x][dt], 0, 0, 0);
        acc[x][dt] = __builtin_amdgcn_mfma_f32_16x16x32_bf16(vf1, pw1[x], acc[x][dt], 0, 0, 0);
      }
    }
  };

  short8 aK0, aK1, aV0, aV1;   // reg set A (even tile of a pair)
  short8 bK0, bK1, bV0, bV1;   // reg set B (odd tile of a pair)

  // ---- prologue: tiles 0,1 -> bufs 0,1
  issue(0, aK0, aK1, aV0, aV1);
  issue(1, bK0, bK1, bV0, bV1);
  publish(kls0, vls0, aK0, aK1, aV0, aV1);
  publish(kls1, vls1, bK0, bK1, bV0, bV1);
  block_sync_lds();

  for (int tp = 0; tp < 8; ++tp) {
    // issue tiles 2tp+2, 2tp+3 (reg sets are free: published at prev tail)
    if (tp < 7) {
      issue(2 * tp + 2, aK0, aK1, aV0, aV1);
      issue(2 * tp + 3, bK0, bK1, bV0, bV1);
    }
    // compute tiles 2tp, 2tp+1 from bufs (2tp)&3, (2tp+1)&3
    const short* kE = (tp & 1) ? kls2 : kls0;
    const short* vE = (tp & 1) ? vls2 : vls0;
    const short* kO = (tp & 1) ? kls3 : kls1;
    const short* vO = (tp & 1) ? vls3 : vls1;
    tilec(kE, vE, 2 * tp);
    tilec(kO, vO, 2 * tp + 1);
    // publish tiles 2tp+2, 2tp+3 into the other buffer pair
    if (tp < 7) {
      short* kEn = (tp & 1) ? kls0 : kls2;
      short* vEn = (tp & 1) ? vls0 : vls2;
      short* kOn = (tp & 1) ? kls1 : kls3;
      short* vOn = (tp & 1) ? vls1 : vls3;
      publish(kEn, vEn, aK0, aK1, aV0, aV1);
      publish(kOn, vOn, bK0, bK1, bV0, bV1);
      block_sync_lds();
    }
  }

#pragma unroll
  for (int x = 0; x < 2; ++x) {
    const float inv = 1.f / fmaxf(lac[x][0], 1e-35f);
    short* aorow = ao + (size_t)(n * SEQ + q00 + x * 64 + lr) * EMBED + h * HDIM;
#pragma unroll
    for (int dt = 0; dt < 4; ++dt) {
      short4v r;
      r[0] = cvt1(acc[x][dt][0] * inv);
      r[1] = cvt1(acc[x][dt][1] * inv);
      r[2] = cvt1(acc[x][dt][2] * inv);
      r[3] = cvt1(acc[x][dt][3] * inv);
      *(short4v*)(aorow + dt * 16 + g * 4) = r;
    }
  }
}

// ---------------------------------------------------------------------------
// Kernel 3: out = ao @ Wu^T + bu.  128x128 tile, 4 waves x 64x64 wave-tile,
// BK=64.  4-buffer LDS rotation (128 KB), one barrier per 2 K-steps:
// issue steps 2tp+2,2tp+3 at pair-head, publish at pair-tail (round-21
// phasing fix).  Counted-vmcnt barriers, 16B-block XOR swizzle.
// Grid 32x8 = 256 blocks = 1/CU.
// ---------------------------------------------------------------------------
__global__ __launch_bounds__(256, 1) void k_gemm(
    const short* __restrict__ ao, const short* __restrict__ wub,
    const float* __restrict__ bu, float* __restrict__ out) {
  const int r0 = blockIdx.x * 128, c0 = blockIdx.y * 128;
  const int t = threadIdx.x;
  const int w = t >> 6, l = t & 63, lr = l & 15, g = l >> 4;
  const int wr = w >> 1, wc = w & 1;   // wave tile: rows wr*64.., cols wc*64..

  __shared__ __align__(16) short als0[8192], als1[8192], als2[8192], als3[8192];
  __shared__ __align__(16) short bls0[8192], bls1[8192], bls2[8192], bls3[8192];

  int ldc[4];
  const short *agp[4], *bgp[4];
#pragma unroll
  for (int j = 0; j < 4; ++j) {
    const int c = t + 256 * j;
    const int row = c >> 3, c8 = c & 7;
    ldc[j] = row * 64 + ((c8 ^ (row & 7)) << 3);
    agp[j] = ao  + (size_t)(r0 + row) * EMBED + c8 * 8;
    bgp[j] = wub + (size_t)(c0 + row) * EMBED + c8 * 8;
  }

  int aoff[4][2], boff[4][2];
#pragma unroll
  for (int fr = 0; fr < 4; ++fr) {
    const int ra = wr * 64 + fr * 16 + lr;
#pragma unroll
    for (int kk = 0; kk < 2; ++kk)
      aoff[fr][kk] = ra * 64 + (((kk * 4 + g) ^ (ra & 7)) << 3);
  }
#pragma unroll
  for (int fc = 0; fc < 4; ++fc) {
    const int rb = wc * 64 + fc * 16 + lr;
#pragma unroll
    for (int kk = 0; kk < 2; ++kk)
      boff[fc][kk] = rb * 64 + (((kk * 4 + g) ^ (rb & 7)) << 3);
  }

  float4v acc[4][4];
#pragma unroll
  for (int fr = 0; fr < 4; ++fr)
#pragma unroll
    for (int fc = 0; fc < 4; ++fc) acc[fr][fc] = (float4v){0.f, 0.f, 0.f, 0.f};

  short8 sAa[4], sBa[4], sAb[4], sBb[4];

  auto issueg = [&](int step, short8* SA, short8* SB) {
    const int kb = step * 64;
#pragma unroll
    for (int j = 0; j < 4; ++j) {
      SA[j] = *(const short8*)(agp[j] + kb);
      SB[j] = *(const short8*)(bgp[j] + kb);
    }
  };
  auto publishg = [&](short* Ad, short* Bd, const short8* SA, const short8* SB) {
#pragma unroll
    for (int j = 0; j < 4; ++j) {
      *(short8*)(Ad + ldc[j]) = SA[j];
      *(short8*)(Bd + ldc[j]) = SB[j];
    }
  };
  auto stepc = [&](const short* Ab, const short* Bb) {
#pragma unroll
    for (int kk = 0; kk < 2; ++kk) {
      short8 bf[4];
#pragma unroll
      for (int fc = 0; fc < 4; ++fc)
        bf[fc] = *(const short8*)(Bb + boff[fc][kk]);
#pragma unroll
      for (int fr = 0; fr < 4; ++fr) {
        short8 af = *(const short8*)(Ab + aoff[fr][kk]);
#pragma unroll
        for (int fc = 0; fc < 4; ++fc)
          acc[fr][fc] = __builtin_amdgcn_mfma_f32_16x16x32_bf16(af, bf[fc], acc[fr][fc], 0, 0, 0);
      }
    }
  };

  // prologue: steps 0,1 -> bufs 0,1
  issueg(0, sAa, sBa);
  issueg(1, sAb, sBb);
  publishg(als0, bls0, sAa, sBa);
  publishg(als1, bls1, sAb, sBb);
  block_sync_lds();

  for (int tp = 0; tp < 8; ++tp) {
    if (tp < 7) {
      issueg(2 * tp + 2, sAa, sBa);
      issueg(2 * tp + 3, sAb, sBb);
    }
    const short* aE = (tp & 1) ? als2 : als0;
    const short* bE = (tp & 1) ? bls2 : bls0;
    const short* aO = (tp & 1) ? als3 : als1;
    const short* bO = (tp & 1) ? bls3 : bls1;
    stepc(aE, bE);
    stepc(aO, bO);
    if (tp < 7) {
      short* aEn = (tp & 1) ? als0 : als2;
      short* bEn = (tp & 1) ? bls0 : bls2;
      short* aOn = (tp & 1) ? als1 : als3;
      short* bOn = (tp & 1) ? bls1 : bls3;
      publishg(aEn, bEn, sAa, sBa);
      publishg(aOn, bOn, sAb, sBb);
      block_sync_lds();
    }
  }

  // epilogue
#pragma unroll
  for (int fc = 0; fc < 4; ++fc) {
    const int col = c0 + wc * 64 + fc * 16 + lr;
    const float bv = bu[col];
#pragma unroll
    for (int fr = 0; fr < 4; ++fr)
#pragma unroll
      for (int i = 0; i < 4; ++i) {
        const int row = r0 + wr * 64 + fr * 16 + g * 4 + i;
        out[(size_t)row * EMBED + col] = acc[fr][fc][i] + bv;
      }
  }
}

// ---------------------------------------------------------------------------
extern "C" void kernel_launch(void* const* d_in, const int* in_sizes, int n_in,
                              void* d_out, int out_size, void* d_ws, size_t ws_size,
                              hipStream_t stream) {
  const float* values = (const float*)d_in[0];
  const float* keys   = (const float*)d_in[1];
  const float* query  = (const float*)d_in[2];
  const int*   mask   = (const int*)d_in[3];
  const float* Wv     = (const float*)d_in[4];
  const float* Wq     = (const float*)d_in[5];
  const float* Wk     = (const float*)d_in[6];
  const float* Wu     = (const float*)d_in[7];
  const float* bu     = (const float*)d_in[8];
  float* out = (float*)d_out;

  char* ws = (char*)d_ws;
  short* qp  = (short*)ws;                        // 8 MB  (4M bf16)
  short* kp  = qp + (1u << 22);                   // 8 MB (rows permuted per 32)
  short* vpT = kp + (1u << 22);                   // 8 MB (plain transposed V)
  short* ao  = vpT + (1u << 22);                  // 8 MB
  unsigned char* maskb = (unsigned char*)(ws + (32u << 20));  // 1 MB nibble bytes
  short* wub = (short*)(ws + (36u << 20));        // 2 MB

  k_pre<<<dim3(1344), 256, 0, stream>>>(values, keys, query, Wv, Wq, Wk, Wu,
                                        mask, qp, kp, vpT, maskb, wub);
  k_attn<<<dim3(512), 256, 0, stream>>>(qp, kp, vpT, maskb, ao);
  k_gemm<<<dim3(32, 8), 256, 0, stream>>>(ao, wub, bu, out);
}

// Round 23
// 73.818 us; speedup vs baseline: 1.0325x; 1.0325x over previous
//
#include <hip/hip_runtime.h>
#include <hip/hip_bf16.h>

#define EMBED 1024
#define HEADS 16
#define HDIM  64
#define BATCH 4
#define SEQ   1024

typedef __attribute__((ext_vector_type(8))) short  short8;
typedef __attribute__((ext_vector_type(4))) short  short4v;
typedef __attribute__((ext_vector_type(4))) float  float4v;
typedef __attribute__((ext_vector_type(8))) float  float8;
typedef __attribute__((ext_vector_type(2))) __bf16 bf16x2;
typedef __attribute__((ext_vector_type(8))) __bf16 bf16x8;

// f32 -> bf16 via native cast (hardware cvt, RNE)
static __device__ __forceinline__ short cvt1(float f) {
  return __builtin_bit_cast(short, (__bf16)f);
}

// pack two f32 -> bf16x2 in one dword (hardware cvt_pk)
static __device__ __forceinline__ unsigned pkbf(float a, float b) {
  bf16x2 v; v[0] = (__bf16)a; v[1] = (__bf16)b;
  return __builtin_bit_cast(unsigned, v);
}

// single v_exp_f32
static __device__ __forceinline__ float ex2(float x) {
  return __builtin_amdgcn_exp2f(x);
}

static __device__ __forceinline__ short8 cvt8(const float* p) {
  float4v a = *(const float4v*)p;
  float4v b = *(const float4v*)(p + 4);
  float8 f = __builtin_shufflevector(a, b, 0, 1, 2, 3, 4, 5, 6, 7);
  bf16x8 bb = __builtin_convertvector(f, bf16x8);
  return __builtin_bit_cast(short8, bb);
}

// Block barrier WITHOUT vmcnt drain (T4).  Cross-wave deps are LDS-only:
// lgkmcnt(0) retires ds_writes AND ds_reads before s_barrier; global loads
// are consumed only by the issuing wave (compiler inserts counted vmcnt).
static __device__ __forceinline__ void block_sync_lds() {
  __builtin_amdgcn_sched_barrier(0);
  asm volatile("s_waitcnt lgkmcnt(0)" ::: "memory");
  __builtin_amdgcn_s_barrier();
  __builtin_amdgcn_sched_barrier(0);
}

#define QSCL 0.04508422002778011f  // log2(e) / sqrt(EMBED)

// ---------------------------------------------------------------------------
// Kernel 1 (fused preprocessing), 1344 blocks — best measured (round 18):
//   blocks 0..767     : proj, 4 waves/block, 4 units/wave, W hoisted.
//   blocks 768..1279  : mask -> nibble bytes (1M quads, 8 iters).
//   blocks 1280..1343 : Wu -> bf16.
// K rows stored PERMUTED within each 32-key block:
//   s(o) = ((o>>2)&1)*16 + (o>>3)*4 + (o&3)
// so packed P dwords form a legal 16x16x32 B-fragment in attn and vpT is a
// plain [d][s] transpose.
// ---------------------------------------------------------------------------
__global__ __launch_bounds__(256) void k_pre(
    const float* __restrict__ values, const float* __restrict__ keys,
    const float* __restrict__ query,
    const float* __restrict__ Wv, const float* __restrict__ Wq,
    const float* __restrict__ Wk, const float* __restrict__ Wu,
    const int* __restrict__ mask,
    short* __restrict__ qp, short* __restrict__ kp, short* __restrict__ vpT,
    unsigned char* __restrict__ maskb, short* __restrict__ wub) {
  const int b = blockIdx.x;
  const int t = threadIdx.x;
  if (b < 768) {
    const int l = t & 63, lr = l & 15, g = l >> 4;
    const int wbase = (b * 4 + (t >> 6)) * 4;
    const int z = wbase >> 12;          // uniform for all 4 units
    const float* in_; const float* Wm;
    if (z == 0)      { in_ = query;  Wm = Wq; }
    else if (z == 1) { in_ = keys;   Wm = Wk; }
    else             { in_ = values; Wm = Wv; }
    const float scl = (z == 0) ? QSCL : 1.0f;

    short8 af0[4], af1[4];
    int hh[4], rr[4];
#pragma unroll
    for (int uu = 0; uu < 4; ++uu) {
      const int rem = (wbase + uu) & 4095;
      hh[uu] = rem & 15;
      rr[uu] = (rem >> 4) * 16;
      af0[uu] = cvt8(in_ + (size_t)(rr[uu] + lr) * EMBED + hh[uu] * HDIM + g * 8);
      af1[uu] = cvt8(in_ + (size_t)(rr[uu] + lr) * EMBED + hh[uu] * HDIM + 32 + g * 8);
    }
    short8 wf0[4], wf1[4];
#pragma unroll
    for (int nt = 0; nt < 4; ++nt) {
      wf0[nt] = cvt8(Wm + (size_t)(nt * 16 + lr) * HDIM + g * 8);
      wf1[nt] = cvt8(Wm + (size_t)(nt * 16 + lr) * HDIM + 32 + g * 8);
    }

#pragma unroll
    for (int uu = 0; uu < 4; ++uu) {
      const int h = hh[uu], r0 = rr[uu];
      const int n = r0 >> 10, s0 = r0 & 1023;
      const int nh = n * HEADS + h;
      float4v acc[4];
#pragma unroll
      for (int nt = 0; nt < 4; ++nt) {
        acc[nt] = (float4v){0.f, 0.f, 0.f, 0.f};
        acc[nt] = __builtin_amdgcn_mfma_f32_16x16x32_bf16(af0[uu], wf0[nt], acc[nt], 0, 0, 0);
        acc[nt] = __builtin_amdgcn_mfma_f32_16x16x32_bf16(af1[uu], wf1[nt], acc[nt], 0, 0, 0);
      }
      if (z == 2) {
#pragma unroll
        for (int nt = 0; nt < 4; ++nt) {
          short4v r;
          r[0]=cvt1(acc[nt][0]); r[1]=cvt1(acc[nt][1]);
          r[2]=cvt1(acc[nt][2]); r[3]=cvt1(acc[nt][3]);
          *(short4v*)(vpT + (size_t)(nh * HDIM + nt * 16 + lr) * SEQ + s0 + g * 4) = r;
        }
      } else {
        short* outp = (z == 0) ? qp : kp;
        const int b8 = ((s0 >> 4) & 1) * 8;
        const int rbase = s0 & ~31;
#pragma unroll
        for (int nt = 0; nt < 4; ++nt)
#pragma unroll
          for (int i = 0; i < 4; ++i) {
            const int row = (z == 0)
                ? (s0 + g * 4 + i)
                : (rbase + (g & 1) * 16 + b8 + (g >> 1) * 4 + i);  // s(o) perm
            outp[(size_t)(nh * SEQ + row) * HDIM + nt * 16 + lr] =
                cvt1(acc[nt][i] * scl);
          }
      }
    }
  } else if (b < 1280) {
    const int q0 = ((b - 768) * 8) * 256 + t;
#pragma unroll
    for (int it = 0; it < 8; ++it) {
      const int q = q0 + it * 256;
      uint4 v = *(const uint4*)(mask + (size_t)q * 4);
      unsigned nib = (v.x ? 1u : 0u) | (v.y ? 2u : 0u) |
                     (v.z ? 4u : 0u) | (v.w ? 8u : 0u);
      maskb[q] = (unsigned char)nib;
    }
  } else {
    const int base = (b - 1280) * 256 + t;
#pragma unroll
    for (int it = 0; it < 16; ++it) {
      int i4 = (base + it * 16384) * 4;
      float4v v = *(const float4v*)(Wu + i4);
      short4v r; r[0]=cvt1(v[0]); r[1]=cvt1(v[1]); r[2]=cvt1(v[2]); r[3]=cvt1(v[3]);
      *(short4v*)(wub + i4) = r;
    }
  }
}

// ---------------------------------------------------------------------------
// Kernel 2: flash attention — best measured (rounds 18-20).  QBLK=128, QG=2,
// nibble mask, mfma32-PV, ones-MFMA l, no max tracking, 2-buffer LDS,
// prefetch distance 2 (reg sets), counted-vmcnt barriers, 16B-block XOR
// swizzle.  XCD-swizzled grid (512 blocks, 2/CU; 32KB LDS).
// ---------------------------------------------------------------------------
__global__ __launch_bounds__(256, 2) void k_attn(
    const short* __restrict__ qp, const short* __restrict__ kp,
    const short* __restrict__ vpT, const unsigned char* __restrict__ maskb,
    short* __restrict__ ao) {
  const int bid = blockIdx.x;
  const int work = (bid & 7) * 64 + (bid >> 3);
  const int qt = work & 7, grp = work >> 3;
  const int h = grp & 15, n = grp >> 4;

  const int t256 = threadIdx.x;
  const int w = t256 >> 6, l = t256 & 63, lr = l & 15, g = l >> 4;
  const int nh = n * HEADS + h;
  const int q00 = qt * 128 + w * 16;   // group x covers rows q00 + x*64 + lr
  const short* qb  = qp  + (size_t)nh * SEQ * HDIM;
  const short* kbp = kp  + (size_t)nh * SEQ * HDIM;
  const short* vb  = vpT + (size_t)nh * HDIM * SEQ;
  const unsigned char* mb0 = maskb + (size_t)(n * SEQ + q00 + lr) * 256;

  __shared__ __align__(16) short kls0[4096], kls1[4096];
  __shared__ __align__(16) short vls0[4096], vls1[4096];

  const int s0 = t256, s1 = t256 + 256;
  const int r0s = s0 >> 3, c0s = s0 & 7, r1s = s1 >> 3, c1s = s1 & 7;
  const int ld0 = r0s * 64 + ((c0s ^ (r0s & 7)) << 3);
  const int ld1 = r1s * 64 + ((c1s ^ (r1s & 7)) << 3);

  const int e = lr & 7;
  const int base0 = lr * 64 + ((g ^ e) << 3);
  const int base1 = lr * 64 + (((4 + g) ^ e) << 3);

  short8 qf0[2], qf1[2];
#pragma unroll
  for (int x = 0; x < 2; ++x) {
    qf0[x] = *(const short8*)(qb + (q00 + x * 64 + lr) * HDIM + g * 8);
    qf1[x] = *(const short8*)(qb + (q00 + x * 64 + lr) * HDIM + 32 + g * 8);
  }

  const short8 ones8 = {0x3F80, 0x3F80, 0x3F80, 0x3F80,
                        0x3F80, 0x3F80, 0x3F80, 0x3F80};

  float4v acc[2][4];
  float4v lac[2];
#pragma unroll
  for (int x = 0; x < 2; ++x) {
    lac[x] = (float4v){0.f, 0.f, 0.f, 0.f};
#pragma unroll
    for (int dt = 0; dt < 4; ++dt) acc[x][dt] = (float4v){0.f, 0.f, 0.f, 0.f};
  }

  auto issue = [&](int tile, short8& K0, short8& K1, short8& V0, short8& V1) {
    const int kn = tile * 64;
    K0 = *(const short8*)(kbp + kn * 64 + s0 * 8);
    K1 = *(const short8*)(kbp + kn * 64 + s1 * 8);
    V0 = *(const short8*)(vb + (size_t)r0s * SEQ + kn + c0s * 8);
    V1 = *(const short8*)(vb + (size_t)r1s * SEQ + kn + c1s * 8);
  };
  auto publish = [&](short* Kd, short* Vd, short8 K0, short8 K1, short8 V0, short8 V1) {
    *(short8*)(Kd + ld0) = K0;
    *(short8*)(Kd + ld1) = K1;
    *(short8*)(Vd + ld0) = V0;
    *(short8*)(Vd + ld1) = V1;
  };
  auto tilec = [&](const short* Kb, const short* Vb, int t) {
    float4v sT[2][4];
#pragma unroll
    for (int a = 0; a < 4; ++a) {
      short8 kf0 = *(const short8*)(Kb + a * 1024 + base0);
      short8 kf1 = *(const short8*)(Kb + a * 1024 + base1);
#pragma unroll
      for (int x = 0; x < 2; ++x) {
        float4v z = (float4v){0.f, 0.f, 0.f, 0.f};
        z = __builtin_amdgcn_mfma_f32_16x16x32_bf16(kf0, qf0[x], z, 0, 0, 0);
        sT[x][a] = __builtin_amdgcn_mfma_f32_16x16x32_bf16(kf1, qf1[x], z, 0, 0, 0);
      }
    }
    short8 pw0[2], pw1[2];
#pragma unroll
    for (int x = 0; x < 2; ++x) {
      uint4 mv = *(const uint4*)(mb0 + (size_t)x * 64 * 256 + t * 16);
      const unsigned wl = (g & 2) ? mv.y : mv.x;
      const unsigned wh = (g & 2) ? mv.w : mv.z;
      const int sh = (g & 1) * 16;
      unsigned dw[8];
#pragma unroll
      for (int a = 0; a < 4; ++a) {
        unsigned ta = ((a & 2) ? wh : wl) >> (sh + (a & 1) * 8);
        float p0 = ex2(sT[x][a][0]); p0 = (ta & 1u) ? p0 : 0.f;
        float p1 = ex2(sT[x][a][1]); p1 = (ta & 2u) ? p1 : 0.f;
        float p2 = ex2(sT[x][a][2]); p2 = (ta & 4u) ? p2 : 0.f;
        float p3 = ex2(sT[x][a][3]); p3 = (ta & 8u) ? p3 : 0.f;
        dw[a * 2]     = pkbf(p0, p1);
        dw[a * 2 + 1] = pkbf(p2, p3);
      }
      __builtin_memcpy(&pw0[x], &dw[0], 16);
      __builtin_memcpy(&pw1[x], &dw[4], 16);
      lac[x] = __builtin_amdgcn_mfma_f32_16x16x32_bf16(ones8, pw0[x], lac[x], 0, 0, 0);
      lac[x] = __builtin_amdgcn_mfma_f32_16x16x32_bf16(ones8, pw1[x], lac[x], 0, 0, 0);
    }
#pragma unroll
    for (int dt = 0; dt < 4; ++dt) {
      short8 vf0 = *(const short8*)(Vb + dt * 1024 + base0);
      short8 vf1 = *(const short8*)(Vb + dt * 1024 + base1);
#pragma unroll
      for (int x = 0; x < 2; ++x) {
        acc[x][dt] = __builtin_amdgcn_mfma_f32_16x16x32_bf16(vf0, pw0[x], acc[x][dt], 0, 0, 0);
        acc[x][dt] = __builtin_amdgcn_mfma_f32_16x16x32_bf16(vf1, pw1[x], acc[x][dt], 0, 0, 0);
      }
    }
  };

  short8 aK0, aK1, aV0, aV1;
  short8 bK0, bK1, bV0, bV1;

  issue(0, aK0, aK1, aV0, aV1);
  publish(kls0, vls0, aK0, aK1, aV0, aV1);
  issue(1, bK0, bK1, bV0, bV1);
  block_sync_lds();

  for (int tp = 0; tp < 8; ++tp) {
    if (tp < 7) issue(2 * tp + 2, aK0, aK1, aV0, aV1);
    tilec(kls0, vls0, 2 * tp);
    publish(kls1, vls1, bK0, bK1, bV0, bV1);
    block_sync_lds();
    if (tp < 7) issue(2 * tp + 3, bK0, bK1, bV0, bV1);
    tilec(kls1, vls1, 2 * tp + 1);
    if (tp < 7) {
      publish(kls0, vls0, aK0, aK1, aV0, aV1);
      block_sync_lds();
    }
  }

#pragma unroll
  for (int x = 0; x < 2; ++x) {
    const float inv = 1.f / fmaxf(lac[x][0], 1e-35f);
    short* aorow = ao + (size_t)(n * SEQ + q00 + x * 64 + lr) * EMBED + h * HDIM;
#pragma unroll
    for (int dt = 0; dt < 4; ++dt) {
      short4v r;
      r[0] = cvt1(acc[x][dt][0] * inv);
      r[1] = cvt1(acc[x][dt][1] * inv);
      r[2] = cvt1(acc[x][dt][2] * inv);
      r[3] = cvt1(acc[x][dt][3] * inv);
      *(short4v*)(aorow + dt * 16 + g * 4) = r;
    }
  }
}

// ---------------------------------------------------------------------------
// Kernel 3: out = ao @ Wu^T + bu — best measured (round 20).  128x128 tile,
// 4 waves x 64x64 wave-tile, BK=64, 2-buffer LDS, prefetch distance 2,
// counted-vmcnt barriers, 16B-block XOR swizzle.  Grid 32x8 = 256 blocks.
// ---------------------------------------------------------------------------
__global__ __launch_bounds__(256, 1) void k_gemm(
    const short* __restrict__ ao, const short* __restrict__ wub,
    const float* __restrict__ bu, float* __restrict__ out) {
  const int r0 = blockIdx.x * 128, c0 = blockIdx.y * 128;
  const int t = threadIdx.x;
  const int w = t >> 6, l = t & 63, lr = l & 15, g = l >> 4;
  const int wr = w >> 1, wc = w & 1;   // wave tile: rows wr*64.., cols wc*64..

  __shared__ __align__(16) short als[2][128 * 64];
  __shared__ __align__(16) short bls[2][128 * 64];

  int ldc[4];
  const short *agp[4], *bgp[4];
#pragma unroll
  for (int j = 0; j < 4; ++j) {
    const int c = t + 256 * j;
    const int row = c >> 3, c8 = c & 7;
    ldc[j] = row * 64 + ((c8 ^ (row & 7)) << 3);
    agp[j] = ao  + (size_t)(r0 + row) * EMBED + c8 * 8;
    bgp[j] = wub + (size_t)(c0 + row) * EMBED + c8 * 8;
  }

  int aoff[4][2], boff[4][2];
#pragma unroll
  for (int fr = 0; fr < 4; ++fr) {
    const int ra = wr * 64 + fr * 16 + lr;
#pragma unroll
    for (int kk = 0; kk < 2; ++kk)
      aoff[fr][kk] = ra * 64 + (((kk * 4 + g) ^ (ra & 7)) << 3);
  }
#pragma unroll
  for (int fc = 0; fc < 4; ++fc) {
    const int rb = wc * 64 + fc * 16 + lr;
#pragma unroll
    for (int kk = 0; kk < 2; ++kk)
      boff[fc][kk] = rb * 64 + (((kk * 4 + g) ^ (rb & 7)) << 3);
  }

  float4v acc[4][4];
#pragma unroll
  for (int fr = 0; fr < 4; ++fr)
#pragma unroll
    for (int fc = 0; fc < 4; ++fc) acc[fr][fc] = (float4v){0.f, 0.f, 0.f, 0.f};

  short8 sAa[4], sBa[4], sAb[4], sBb[4];

  auto issueg = [&](int step, short8* SA, short8* SB) {
    const int kb = step * 64;
#pragma unroll
    for (int j = 0; j < 4; ++j) {
      SA[j] = *(const short8*)(agp[j] + kb);
      SB[j] = *(const short8*)(bgp[j] + kb);
    }
  };
  auto publishg = [&](short* Ad, short* Bd, const short8* SA, const short8* SB) {
#pragma unroll
    for (int j = 0; j < 4; ++j) {
      *(short8*)(Ad + ldc[j]) = SA[j];
      *(short8*)(Bd + ldc[j]) = SB[j];
    }
  };
  auto stepc = [&](const short* Ab, const short* Bb) {
#pragma unroll
    for (int kk = 0; kk < 2; ++kk) {
      short8 bf[4];
#pragma unroll
      for (int fc = 0; fc < 4; ++fc)
        bf[fc] = *(const short8*)(Bb + boff[fc][kk]);
#pragma unroll
      for (int fr = 0; fr < 4; ++fr) {
        short8 af = *(const short8*)(Ab + aoff[fr][kk]);
#pragma unroll
        for (int fc = 0; fc < 4; ++fc)
          acc[fr][fc] = __builtin_amdgcn_mfma_f32_16x16x32_bf16(af, bf[fc], acc[fr][fc], 0, 0, 0);
      }
    }
  };

  // prologue: step 0 -> buf0; step 1 -> set B
  issueg(0, sAa, sBa);
  publishg(&als[0][0], &bls[0][0], sAa, sBa);
  issueg(1, sAb, sBb);
  block_sync_lds();

  for (int tp = 0; tp < 8; ++tp) {
    if (tp < 7) issueg(2 * tp + 2, sAa, sBa);
    stepc(&als[0][0], &bls[0][0]);
    publishg(&als[1][0], &bls[1][0], sAb, sBb);
    block_sync_lds();
    if (tp < 7) issueg(2 * tp + 3, sAb, sBb);
    stepc(&als[1][0], &bls[1][0]);
    if (tp < 7) {
      publishg(&als[0][0], &bls[0][0], sAa, sBa);
      block_sync_lds();
    }
  }

  // epilogue
#pragma unroll
  for (int fc = 0; fc < 4; ++fc) {
    const int col = c0 + wc * 64 + fc * 16 + lr;
    const float bv = bu[col];
#pragma unroll
    for (int fr = 0; fr < 4; ++fr)
#pragma unroll
      for (int i = 0; i < 4; ++i) {
        const int row = r0 + wr * 64 + fr * 16 + g * 4 + i;
        out[(size_t)row * EMBED + col] = acc[fr][fc][i] + bv;
      }
  }
}

// ---------------------------------------------------------------------------
extern "C" void kernel_launch(void* const* d_in, const int* in_sizes, int n_in,
                              void* d_out, int out_size, void* d_ws, size_t ws_size,
                              hipStream_t stream) {
  const float* values = (const float*)d_in[0];
  const float* keys   = (const float*)d_in[1];
  const float* query  = (const float*)d_in[2];
  const int*   mask   = (const int*)d_in[3];
  const float* Wv     = (const float*)d_in[4];
  const float* Wq     = (const float*)d_in[5];
  const float* Wk     = (const float*)d_in[6];
  const float* Wu     = (const float*)d_in[7];
  const float* bu     = (const float*)d_in[8];
  float* out = (float*)d_out;

  char* ws = (char*)d_ws;
  short* qp  = (short*)ws;                        // 8 MB  (4M bf16)
  short* kp  = qp + (1u << 22);                   // 8 MB (rows permuted per 32)
  short* vpT = kp + (1u << 22);                   // 8 MB (plain transposed V)
  short* ao  = vpT + (1u << 22);                  // 8 MB
  unsigned char* maskb = (unsigned char*)(ws + (32u << 20));  // 1 MB nibble bytes
  short* wub = (short*)(ws + (36u << 20));        // 2 MB

  k_pre<<<dim3(1344), 256, 0, stream>>>(values, keys, query, Wv, Wq, Wk, Wu,
                                        mask, qp, kp, vpT, maskb, wub);
  k_attn<<<dim3(512), 256, 0, stream>>>(qp, kp, vpT, maskb, ao);
  k_gemm<<<dim3(32, 8), 256, 0, stream>>>(ao, wub, bu, out);
}